// Round 9
// baseline (680.402 us; speedup 1.0000x reference)
//
#include <hip/hip_runtime.h>
#include <math.h>

#define NF 128      // feature/hidden dim (F == H == 128)
#define NU 64       // uints per bf16 row (NF/2) — last layer output + pool
#define NQ 32       // uints per fp8 row (NF/4) — inter-layer activations
#define TROWS 32    // fused-kernel tile rows
#define ARS 68      // As row stride in u32 (64 + 4 pad)
#define CRS 132     // Cs row stride in floats (128 + 4 pad)
#define QS  16.0f   // fp8 storage scale (folded into pack)
#define QIS 0.0625f // 1/QS (applied in epilogue before bias)

#define SRC_BITS 18             // src node id bits in packed pair (n < 262144)
#define SRC_MASK ((1u << SRC_BITS) - 1u)
#define BCS 32                  // bucket counter stride (ints) -> 1 line/bucket
#define EPB 2048                // edges per block in bucket scatter
#define NSL 4                   // source slices (each (n+3)/4 rows = 3.2MB fp8)

typedef unsigned int  u32;
typedef unsigned short u16;
typedef u32 b4 __attribute__((ext_vector_type(2)));     // 4 bf16 (8B)
typedef short bf16x8 __attribute__((ext_vector_type(8)));  // MFMA A/B frag (16B)
typedef float f32x4 __attribute__((ext_vector_type(4)));   // MFMA C/D frag
typedef float f32x2 __attribute__((ext_vector_type(2)));   // cvt_pk_f32_fp8 result

__device__ inline u16 f2bf(float f) {               // RNE float->bf16
    u32 u = __float_as_uint(f);
    return (u16)((u + 0x7fffu + ((u >> 16) & 1u)) >> 16);
}
__device__ inline u32 pack2(float a, float b) {     // ch2k=lo, ch2k+1=hi
    return (u32)f2bf(a) | ((u32)f2bf(b) << 16);
}
__device__ inline float bflo(u32 u) { return __uint_as_float(u << 16); }
__device__ inline float bfhi(u32 u) { return __uint_as_float(u & 0xffff0000u); }

// 4 consecutive channels -> 4 fp8 e4m3 bytes (byte0 = first channel)
__device__ inline u32 pack4(float a, float b, float c, float d) {
    u32 v = __builtin_amdgcn_cvt_pk_fp8_f32(a, b, 0, false);
    v = __builtin_amdgcn_cvt_pk_fp8_f32(c, d, v, true);
    return v;
}
// unpack 4 fp8 bytes and accumulate into float4
__device__ inline void acc4(float4& a, u32 q) {
    f32x2 lo = __builtin_amdgcn_cvt_pk_f32_fp8(q, false);
    f32x2 hi = __builtin_amdgcn_cvt_pk_f32_fp8(q, true);
    a.x += lo[0]; a.y += lo[1]; a.z += hi[0]; a.w += hi[1];
}

// ---------- bucket-sort CSR build (fixed-capacity buckets, slice sub-lists) ----------

// A: scatter packed (rel_dst<<SRC_BITS | src) into fixed-capacity buckets.
__global__ __launch_bounds__(256) void k_bscat(const int* __restrict__ ei,
                                               int* bcur, u32* __restrict__ pairs,
                                               int E, int bshift, int cap) {
    __shared__ int h[256];
    __shared__ int rb[256];
    int t = threadIdx.x;
    h[t] = 0;
    __syncthreads();
    int base = blockIdx.x * EPB;
    #pragma unroll
    for (int k = 0; k < EPB / 256; ++k) {
        int e = base + k * 256 + t;
        if (e < E) atomicAdd(&h[ei[E + e] >> bshift], 1);
    }
    __syncthreads();
    int c = h[t];
    if (c) rb[t] = t * cap + atomicAdd(&bcur[t * BCS], c);
    h[t] = 0;
    __syncthreads();
    #pragma unroll
    for (int k = 0; k < EPB / 256; ++k) {
        int e = base + k * 256 + t;
        if (e < E) {
            int d = ei[E + e];
            int b = d >> bshift;
            int p = rb[b] + atomicAdd(&h[b], 1);
            u32 rel = (u32)(d - (b << bshift));
            pairs[p] = (rel << SRC_BITS) | (u32)ei[e];
        }
    }
}

// B: per-bucket per-(node,slice) LDS degree histogram -> dinv + bucket-local
// exclusive scan of padded sub-list spans -> offs/offsS4 (LOCAL) + bsum[b].
// Each sub-list padded to x4 (self-loop counted into its own source slice).
__global__ __launch_bounds__(512) void k_degscan(const u32* __restrict__ pairs,
        const int* __restrict__ bcur, float* __restrict__ dinv,
        int* __restrict__ offs, int* __restrict__ offsS4, int* __restrict__ bsum,
        int n, int bshift, int cap, int slw) {
    extern __shared__ int sh[];           // deg[bsz*4] + ss[512]
    int bsz = 1 << bshift;
    int* deg = sh;
    int* ss = sh + bsz * 4;
    int b = blockIdx.x, b0 = b << bshift, t = threadIdx.x;
    for (int i = t; i < bsz * 4; i += 512) deg[i] = 0;
    __syncthreads();
    int lo = b * cap, hi = lo + bcur[b * BCS];
    for (int j = lo + t; j < hi; j += 512) {
        u32 v = pairs[j];
        int rel = v >> SRC_BITS;
        int src = (int)(v & SRC_MASK);
        int s = src / slw; if (s > 3) s = 3;
        atomicAdd(&deg[rel * 4 + s], 1);
    }
    __syncthreads();
    int C = bsz >> 9;                     // nodes per thread (1 for bsz=512)
    int vst[8];
    int tsum = 0;
    for (int c = 0; c < C; ++c) {
        int i = t * C + c;
        int node = b0 + i;
        vst[c] = tsum;
        if (node < n) {
            int ssl = node / slw; if (ssl > 3) ssl = 3;
            int real = 1;                 // self-loop
            #pragma unroll
            for (int s = 0; s < 4; ++s) {
                int cc = deg[i * 4 + s] + (s == ssl ? 1 : 0);
                real += deg[i * 4 + s];
                tsum += (cc + 3) & ~3;
            }
            dinv[node] = 1.0f / sqrtf((float)real);
        }
    }
    ss[t] = tsum;
    for (int d = 1; d < 512; d <<= 1) {
        __syncthreads();
        int a = (t >= d) ? ss[t - d] : 0;
        __syncthreads();
        ss[t] += a;
    }
    __syncthreads();
    int tbase = ss[t] - tsum;             // exclusive
    for (int c = 0; c < C; ++c) {
        int i = t * C + c;
        int node = b0 + i;
        if (node < n) {
            int pos = tbase + vst[c];
            offs[node] = pos;             // bucket-local
            int ssl = node / slw; if (ssl > 3) ssl = 3;
            #pragma unroll
            for (int s = 0; s < 4; ++s) {
                offsS4[node * 4 + s] = pos;
                int cc = deg[i * 4 + s] + (s == ssl ? 1 : 0);
                pos += (cc + 3) & ~3;
            }
        }
    }
    if (t == 511) bsum[b] = ss[511];
}

// C: per-bucket CSR scatter with per-(node,slice) LDS cursors; in-LDS scan of
// bucket totals, finalize offs/offsS4 ABSOLUTE in-place, scatter edges into
// their slice sub-lists, self-loop into its slice, sentinel-pad each sub-list.
__global__ __launch_bounds__(512) void k_csr(const u32* __restrict__ pairs,
        const int* __restrict__ bcur, const int* __restrict__ bsum,
        int* __restrict__ offs, int* __restrict__ offsS4, int* __restrict__ srcS,
        int n, int nbk, int bshift, int cap, int slw) {
    extern __shared__ int sh[];           // cur[bsz*4] + endv[bsz*4]
    __shared__ int ss[512];
    int bsz = 1 << bshift;
    int* cur = sh;
    int* endv = sh + bsz * 4;
    int b = blockIdx.x, b0 = b << bshift, t = threadIdx.x;

    int v = (t < nbk) ? bsum[t] : 0;
    ss[t] = v;
    for (int d = 1; d < 512; d <<= 1) {
        __syncthreads();
        int a = (t >= d) ? ss[t - d] : 0;
        __syncthreads();
        ss[t] += a;
    }
    __syncthreads();
    int base = ss[b] - bsum[b];           // exclusive base of bucket b
    int nextbase = ss[b];                 // exclusive base of bucket b+1
    int total = ss[511];                  // grand total (padded)
    if (b == nbk - 1 && t == 0) offs[n] = total;

    for (int i = t; i < bsz; i += 512) {
        int node = b0 + i;
        if (node < n) {
            offs[node] += base;
            int4 o4 = *(int4*)(offsS4 + node * 4);
            o4.x += base; o4.y += base; o4.z += base; o4.w += base;
            *(int4*)(offsS4 + node * 4) = o4;
            cur[i * 4 + 0] = o4.x; cur[i * 4 + 1] = o4.y;
            cur[i * 4 + 2] = o4.z; cur[i * 4 + 3] = o4.w;
        } else {
            cur[i * 4 + 0] = 0; cur[i * 4 + 1] = 0;
            cur[i * 4 + 2] = 0; cur[i * 4 + 3] = 0;
        }
    }
    __syncthreads();
    for (int i = t; i < bsz; i += 512) {
        int node = b0 + i;
        if (node < n) {
            endv[i * 4 + 0] = cur[i * 4 + 1];
            endv[i * 4 + 1] = cur[i * 4 + 2];
            endv[i * 4 + 2] = cur[i * 4 + 3];
            int e3;
            if (node + 1 >= n)    e3 = total;
            else if (i < bsz - 1) e3 = cur[(i + 1) * 4 + 0];
            else                  e3 = nextbase;
            endv[i * 4 + 3] = e3;
        }
    }
    __syncthreads();
    int lo = b * cap, hi = lo + bcur[b * BCS];
    for (int j = lo + t; j < hi; j += 512) {
        u32 vv = pairs[j];
        int rel = vv >> SRC_BITS;
        int src = (int)(vv & SRC_MASK);
        int s = src / slw; if (s > 3) s = 3;
        int p = atomicAdd(&cur[rel * 4 + s], 1);
        srcS[p] = src;
    }
    __syncthreads();
    for (int i = t; i < bsz; i += 512) {
        int node = b0 + i;
        if (node < n) {
            int ssl = node / slw; if (ssl > 3) ssl = 3;
            int p = cur[i * 4 + ssl]++;               // self-loop (single owner)
            srcS[p] = node;
            #pragma unroll
            for (int s = 0; s < 4; ++s) {
                int c = cur[i * 4 + s];
                int e = endv[i * 4 + s];
                for (int k = c; k < e; ++k) srcS[k] = n;   // sentinel padding
            }
        }
    }
}

// D: fp8 pack of x (q0[row] = fp8(QS*dinv*x), row n zeros) + pre-swizzled
// bf16 B-fragments of the 4 weight matrices. x loaded NT (read-once stream).
__global__ __launch_bounds__(256) void k_pack(const float* __restrict__ x,
                       const float* __restrict__ dinv, u32* __restrict__ q,
                       const float* __restrict__ W0, const float* __restrict__ W1,
                       const float* __restrict__ W2, const float* __restrict__ W3,
                       u32* __restrict__ wt, int n) {
    int t = blockIdx.x * blockDim.x + threadIdx.x;
    int totalu4 = (n + 1) * (NQ / 4);     // 8 uint4 per fp8 row
    if (t < totalu4) {
        int row = t >> 3;
        uint4 o = make_uint4(0, 0, 0, 0);
        if (row < n) {
            int cbase = (t & 7) << 4;     // 16 channels per uint4
            const float* xr = x + (size_t)row * NF + cbase;
            f32x4 f0 = __builtin_nontemporal_load((const f32x4*)(xr));
            f32x4 f1 = __builtin_nontemporal_load((const f32x4*)(xr + 4));
            f32x4 f2 = __builtin_nontemporal_load((const f32x4*)(xr + 8));
            f32x4 f3 = __builtin_nontemporal_load((const f32x4*)(xr + 12));
            float d = dinv[row] * QS;
            o.x = pack4(f0.x * d, f0.y * d, f0.z * d, f0.w * d);
            o.y = pack4(f1.x * d, f1.y * d, f1.z * d, f1.w * d);
            o.z = pack4(f2.x * d, f2.y * d, f2.z * d, f2.w * d);
            o.w = pack4(f3.x * d, f3.y * d, f3.z * d, f3.w * d);
        }
        ((uint4*)q)[t] = o;
    }
    if (t < 4 * 2048) {
        int layer = t >> 11;
        int rem = t & 2047;               // = (nt*4+ks)*64 + lane
        int lane = rem & 63;
        int ks = (rem >> 6) & 3;
        int nt = rem >> 8;
        const float* W = layer == 0 ? W0 : layer == 1 ? W1 : layer == 2 ? W2 : W3;
        int nn = nt * 16 + (lane & 15);
        int k0 = ks * 32 + (lane >> 4) * 8;
        uint4 o;
        o.x = pack2(W[(k0 + 0) * NF + nn], W[(k0 + 1) * NF + nn]);
        o.y = pack2(W[(k0 + 2) * NF + nn], W[(k0 + 3) * NF + nn]);
        o.z = pack2(W[(k0 + 4) * NF + nn], W[(k0 + 5) * NF + nn]);
        o.w = pack2(W[(k0 + 6) * NF + nn], W[(k0 + 7) * NF + nn]);
        ((uint4*)wt)[t] = o;
    }
}

// ---------- fused layer: slice-phased fp8 gather-sum -> MFMA GEMM -> epilogue ----------
// hin rows fp8 e4m3 (row n zeros). Gather = r7's proven 32-lane/row mapping,
// but edge lists are split into 4 SOURCE-SLICE sub-lists (3.2MB of hin each,
// < 4MB per-XCD L2). Slice loop OUTERMOST with a barrier per slice: all 2048
// persistent blocks start together -> at any instant the GPU references ~one
// slice -> hin reuse hits L2 instead of re-fetching over the fabric (breaks
// the hit-rate/concurrency tradeoff seen r6/r8). acc[4] persists in regs.
__global__ __launch_bounds__(256, 8) void k_fused(
        const u32* __restrict__ hin, const int* __restrict__ offs,
        const int* __restrict__ offsS4, const int* __restrict__ srcS,
        const float* __restrict__ dinv, const u32* __restrict__ wt,
        const float* __restrict__ bias, u32* __restrict__ out,
        int* tctr, int n, int ntiles, int last) {
    __shared__ __align__(16) u32 buf[TROWS * CRS];   // 16.9 KB union As/Cs
    __shared__ int stile;
    float* Cs = (float*)buf;
    int tid = threadIdx.x;
    int grp = tid >> 5;          // 0..7 (gather/epilogue groups)
    int lane32 = tid & 31;
    int c4 = lane32 << 2;        // channel offset (4 ch/lane)
    int cu = lane32 << 1;        // uint offset within bf16 row
    int cq = lane32;             // uint offset within fp8 row
    int wv = tid >> 6;           // wave 0..3 (MFMA phase)
    int lane = tid & 63;
    int m0 = (wv & 1) * 16;      // M-tile base row
    int nh = wv >> 1;            // N-half (cols nh*64..+64)
    int mrow = lane & 15, quad = lane >> 4;

    float4 bv = *(const float4*)(bias + c4);   // constant across tiles

    for (;;) {
        if (tid == 0) stile = atomicAdd(tctr, 1);
        __syncthreads();
        int tile = stile;
        if (tile >= ntiles) break;
        int row0 = tile * TROWS;

        // ---- gather/sum phase: slice-outer, rows-inner, fp32 acc in regs ----
        float4 acc[4];
        #pragma unroll
        for (int i = 0; i < 4; ++i) acc[i] = make_float4(0.f, 0.f, 0.f, 0.f);
        #pragma unroll
        for (int s = 0; s < NSL; ++s) {
            #pragma unroll
            for (int i = 0; i < 4; ++i) {
                int node = row0 + grp * 4 + i;
                if (node < n) {
                    int b = offsS4[node * 4 + s];
                    int e = (s < NSL - 1) ? offsS4[node * 4 + s + 1]
                                          : offs[node + 1];
                    int j = b;
                    for (; j + 8 <= e; j += 8) {
                        int4 sa = *(const int4*)(srcS + j);
                        int4 sb = *(const int4*)(srcS + j + 4);
                        u32 q0 = hin[(size_t)sa.x * NQ + cq];
                        u32 q1 = hin[(size_t)sa.y * NQ + cq];
                        u32 q2 = hin[(size_t)sa.z * NQ + cq];
                        u32 q3 = hin[(size_t)sa.w * NQ + cq];
                        u32 q4 = hin[(size_t)sb.x * NQ + cq];
                        u32 q5 = hin[(size_t)sb.y * NQ + cq];
                        u32 q6 = hin[(size_t)sb.z * NQ + cq];
                        u32 q7 = hin[(size_t)sb.w * NQ + cq];
                        acc4(acc[i], q0); acc4(acc[i], q1);
                        acc4(acc[i], q2); acc4(acc[i], q3);
                        acc4(acc[i], q4); acc4(acc[i], q5);
                        acc4(acc[i], q6); acc4(acc[i], q7);
                    }
                    if (j < e) {             // sub-lists padded x4 -> tail == 4
                        int4 sa = *(const int4*)(srcS + j);
                        u32 q0 = hin[(size_t)sa.x * NQ + cq];
                        u32 q1 = hin[(size_t)sa.y * NQ + cq];
                        u32 q2 = hin[(size_t)sa.z * NQ + cq];
                        u32 q3 = hin[(size_t)sa.w * NQ + cq];
                        acc4(acc[i], q0); acc4(acc[i], q1);
                        acc4(acc[i], q2); acc4(acc[i], q3);
                    }
                }
            }
            __syncthreads();   // keep the whole block phase-aligned per slice
        }
        #pragma unroll
        for (int i = 0; i < 4; ++i) {
            int r = grp * 4 + i;
            int node = row0 + r;
            float4 a = acc[i];
            if (node < n) {
                float dn = dinv[node];
                a.x *= dn; a.y *= dn; a.z *= dn; a.w *= dn;
            }
            b4 o; o.x = pack2(a.x, a.y); o.y = pack2(a.z, a.w);
            *(b4*)(buf + r * ARS + cu) = o;
        }
        __syncthreads();

        // ---- MFMA GEMM phase ----
        f32x4 a0 = {0.f, 0.f, 0.f, 0.f}, a1 = a0, a2 = a0, a3 = a0;
        #pragma unroll
        for (int ks = 0; ks < 4; ++ks) {
            bf16x8 a = *(const bf16x8*)(buf + (m0 + mrow) * ARS + ks * 16 + quad * 4);
            const u32* wb = wt + (((nh * 4) * 4 + ks) * 64 + lane) * 4;
            bf16x8 b0 = *(const bf16x8*)(wb);
            bf16x8 b1 = *(const bf16x8*)(wb + 1024);   // nt+1 -> +256 uint4
            bf16x8 b2 = *(const bf16x8*)(wb + 2048);
            bf16x8 b3 = *(const bf16x8*)(wb + 3072);
            a0 = __builtin_amdgcn_mfma_f32_16x16x32_bf16(a, b0, a0, 0, 0, 0);
            a1 = __builtin_amdgcn_mfma_f32_16x16x32_bf16(a, b1, a1, 0, 0, 0);
            a2 = __builtin_amdgcn_mfma_f32_16x16x32_bf16(a, b2, a2, 0, 0, 0);
            a3 = __builtin_amdgcn_mfma_f32_16x16x32_bf16(a, b3, a3, 0, 0, 0);
        }
        __syncthreads();   // all As reads done before Cs overwrites the union

        // C frags -> LDS (col = lane&15, row = quad*4+reg)
        #pragma unroll
        for (int nt = 0; nt < 4; ++nt) {
            f32x4 av = nt == 0 ? a0 : nt == 1 ? a1 : nt == 2 ? a2 : a3;
            int col = (nh * 4 + nt) * 16 + mrow;
            #pragma unroll
            for (int rg = 0; rg < 4; ++rg)
                Cs[(m0 + quad * 4 + rg) * CRS + col] = av[rg];
        }
        __syncthreads();

        // ---- epilogue: descale + bias + ReLU, pack, plain store ----
        #pragma unroll
        for (int j = 0; j < 4; ++j) {
            int r = grp * 4 + j;
            int gr = row0 + r;
            if (gr <= n) {
                if (last) {
                    b4 o; o.x = 0u; o.y = 0u;
                    if (gr < n) {
                        float4 v = *(const float4*)(Cs + r * CRS + c4);
                        float ox = fmaxf(v.x * QIS + bv.x, 0.f);
                        float oy = fmaxf(v.y * QIS + bv.y, 0.f);
                        float oz = fmaxf(v.z * QIS + bv.z, 0.f);
                        float ow = fmaxf(v.w * QIS + bv.w, 0.f);
                        o.x = pack2(ox, oy);
                        o.y = pack2(oz, ow);
                    }
                    *(b4*)(out + (size_t)gr * NU + cu) = o;   // gr==n keeps sentinel 0
                } else {
                    u32 o = 0u;
                    if (gr < n) {
                        float4 v = *(const float4*)(Cs + r * CRS + c4);
                        float sc = dinv[gr] * QS;
                        float ox = fmaxf(v.x * QIS + bv.x, 0.f) * sc;
                        float oy = fmaxf(v.y * QIS + bv.y, 0.f) * sc;
                        float oz = fmaxf(v.z * QIS + bv.z, 0.f) * sc;
                        float ow = fmaxf(v.w * QIS + bv.w, 0.f) * sc;
                        o = pack4(ox, oy, oz, ow);
                    }
                    out[(size_t)gr * NQ + cq] = o;            // gr==n keeps sentinel 0
                }
            }
        }
        __syncthreads();   // buf reused as As next tile; stile rewrite safe
    }
}

// ---------- fused pool + head (batch sorted -> contiguous ranges; bounds inline) ----------

__global__ __launch_bounds__(256) void k_poolfinal(const u32* __restrict__ h,
        const int* __restrict__ batch, const float* __restrict__ linW,
        const float* __restrict__ linb, float* __restrict__ outp, int N) {
    int g = blockIdx.x;
    int tid = threadIdx.x;
    __shared__ int sb[2];
    if (tid < 2) {                       // lower_bound(batch, g+tid)
        int target = g + tid;
        int lo = 0, hi = N;
        while (lo < hi) {
            int mid = (lo + hi) >> 1;
            if (batch[mid] < target) lo = mid + 1; else hi = mid;
        }
        sb[tid] = lo;
    }
    __syncthreads();
    int b = sb[0], e = sb[1];

    int grp = tid >> 5, lane = tid & 31;
    int c4 = lane << 2, cu = lane << 1;
    float4 acc = make_float4(0.f, 0.f, 0.f, 0.f);
    for (int i = b + grp; i < e; i += 8) {
        b4 v = *(const b4*)(h + (size_t)i * NU + cu);
        acc.x += bflo(v.x); acc.y += bfhi(v.x);
        acc.z += bflo(v.y); acc.w += bfhi(v.y);
    }
    __shared__ float red[8][NF];
    *(float4*)(&red[grp][c4]) = acc;
    __syncthreads();

    float v0 = 0.f, v1 = 0.f;
    if (tid < NF) {
        float s = 0.f;
        #pragma unroll
        for (int gg = 0; gg < 8; ++gg) s += red[gg][tid];
        v0 = s * linW[tid * 2 + 0];
        v1 = s * linW[tid * 2 + 1];
    }
    #pragma unroll
    for (int d = 32; d > 0; d >>= 1) {
        v0 += __shfl_down(v0, d);
        v1 += __shfl_down(v1, d);
    }
    __shared__ float sv[8];
    if ((tid & 63) == 0) { sv[(tid >> 6) * 2] = v0; sv[(tid >> 6) * 2 + 1] = v1; }
    __syncthreads();
    if (tid == 0) {
        float inv = 1.0f / fmaxf((float)(e - b), 1.0f);
        outp[g * 2 + 0] = (sv[0] + sv[2]) * inv + linb[0];
        outp[g * 2 + 1] = (sv[1] + sv[3]) * inv + linb[1];
    }
}

// ---------- launcher ----------

extern "C" void kernel_launch(void* const* d_in, const int* in_sizes, int n_in,
                              void* d_out, int out_size, void* d_ws, size_t ws_size,
                              hipStream_t stream) {
    const float* x     = (const float*)d_in[0];
    const int*   ei    = (const int*)d_in[1];
    const int*   batch = (const int*)d_in[2];
    const float* Wl[4] = {(const float*)d_in[3], (const float*)d_in[5],
                          (const float*)d_in[7], (const float*)d_in[9]};
    const float* bl[4] = {(const float*)d_in[4], (const float*)d_in[6],
                          (const float*)d_in[8], (const float*)d_in[10]};
    const float* linW  = (const float*)d_in[11];
    const float* linb  = (const float*)d_in[12];
    float* out = (float*)d_out;

    const int N  = in_sizes[2];
    const int E  = in_sizes[1] / 2;
    const int G  = out_size / 2;

    // bucket geometry: <=256 buckets, each 1<<bshift nodes
    int bshift = 9;
    while (((N + (1 << bshift) - 1) >> bshift) > 256) ++bshift;
    int nbk = (N + (1 << bshift) - 1) >> bshift;
    int bsz = 1 << bshift;
    // fixed bucket capacity: 1.25x mean + 1024 slack (>=30 sigma), 256-aligned
    int cap = ((E / nbk) * 5 / 4 + 1024 + 255) & ~255;
    int slw = (N + NSL - 1) / NSL;        // source slice width (rows)

    // carve workspace (256B-aligned slices)
    char* p = (char*)d_ws;
    auto carve = [&](size_t bytes) -> char* {
        char* r = p;
        p += (bytes + 255) & ~(size_t)255;
        return r;
    };
    float* dinv   = (float*)carve((size_t)N * 4);
    int*   offs   = (int*)  carve((size_t)(N + 1) * 4);
    int*   offsS4 = (int*)  carve((size_t)N * 4 * 4);          // slice sub-list starts
    int*   bsum   = (int*)  carve(512 * 4);
    int*   bcur   = (int*)  carve(256 * BCS * 4);   // |-- contiguous zeroed region
    int*   tctr   = (int*)  carve(4 * 4);           // |-- end (dyn tile counters)
    u32*   wt     = (u32*)  carve(4 * 2048 * 16);              // bf16 W fragments
    int*   srcS   = (int*)  carve((size_t)(E + 20 * (size_t)N) * 4);  // padded CSR
    u32*   bufA   = (u32*)  carve((size_t)(N + 1) * NU * 4);   // ping (fp8/bf16 rows)
    u32*   bufB   = (u32*)  carve((size_t)(N + 1) * NU * 4);   // pong
    u32*   pairs  = bufB;   // fixed-cap bucketed edges; bufB free until layer-0 out

    size_t zbytes = (char*)(tctr + 4) - (char*)bcur;   // bcur..tctr contiguous
    (void)hipMemsetAsync(bcur, 0, zbytes, stream);

    int nblkE = (E + EPB - 1) / EPB;
    k_bscat<<<nblkE, 256, 0, stream>>>(ei, bcur, pairs, E, bshift, cap);
    k_degscan<<<nbk, 512, (bsz * 4 + 512) * 4, stream>>>(pairs, bcur, dinv, offs,
                                                         offsS4, bsum, N, bshift,
                                                         cap, slw);
    k_csr<<<nbk, 512, bsz * 8 * 4, stream>>>(pairs, bcur, bsum, offs, offsS4,
                                             srcS, N, nbk, bshift, cap, slw);

    int totalu4 = (N + 1) * (NQ / 4);
    int packT = totalu4 > 8192 ? totalu4 : 8192;
    k_pack<<<(packT + 255) / 256, 256, 0, stream>>>(x, dinv, bufA,
                                                    Wl[0], Wl[1], Wl[2], Wl[3], wt, N);

    int ntiles = (N + 1 + TROWS - 1) / TROWS;
    int ngrid = ntiles < 2048 ? ntiles : 2048;
    const u32* hin = bufA;
    u32* hout = bufB;
    for (int l = 0; l < 4; ++l) {
        k_fused<<<ngrid, 256, 0, stream>>>(hin, offs, offsS4, srcS, dinv,
                                           wt + l * 8192, bl[l], hout,
                                           tctr + l, N, ntiles, l == 3);
        hin = hout;
        hout = (hout == bufA) ? bufB : bufA;
    }

    k_poolfinal<<<G, 256, 0, stream>>>(hin, batch, linW, linb, out, N);
}

// Round 10
// 534.736 us; speedup vs baseline: 1.2724x; 1.2724x over previous
//
#include <hip/hip_runtime.h>
#include <math.h>

#define NF 128      // feature/hidden dim (F == H == 128)
#define NU 64       // uints per bf16 row (NF/2) — last layer output + pool
#define NQ 32       // uints per fp8 row (NF/4) — inter-layer activations
#define TROWS 32    // fused-kernel tile rows
#define ARS 68      // As row stride in u32 (64 + 4 pad)
#define CRS 132     // Cs row stride in floats (128 + 4 pad)
#define QS  16.0f   // fp8 storage scale (folded into pack)
#define QIS 0.0625f // 1/QS (applied in epilogue before bias)

#define SRC_BITS 18             // src node id bits in packed pair (n < 262144)
#define SRC_MASK ((1u << SRC_BITS) - 1u)
#define BCS 32                  // bucket counter stride (ints) -> 1 line/bucket
#define EPB 2048                // edges per block in bucket scatter

typedef unsigned int  u32;
typedef unsigned short u16;
typedef u32 b4 __attribute__((ext_vector_type(2)));     // 4 bf16 (8B)
typedef short bf16x8 __attribute__((ext_vector_type(8)));  // MFMA A/B frag (16B)
typedef float f32x4 __attribute__((ext_vector_type(4)));   // MFMA C/D frag
typedef float f32x2 __attribute__((ext_vector_type(2)));   // cvt_pk_f32_fp8 result

__device__ inline u16 f2bf(float f) {               // RNE float->bf16
    u32 u = __float_as_uint(f);
    return (u16)((u + 0x7fffu + ((u >> 16) & 1u)) >> 16);
}
__device__ inline u32 pack2(float a, float b) {     // ch2k=lo, ch2k+1=hi
    return (u32)f2bf(a) | ((u32)f2bf(b) << 16);
}
__device__ inline float bflo(u32 u) { return __uint_as_float(u << 16); }
__device__ inline float bfhi(u32 u) { return __uint_as_float(u & 0xffff0000u); }

// 4 consecutive channels -> 4 fp8 e4m3 bytes (byte0 = first channel)
__device__ inline u32 pack4(float a, float b, float c, float d) {
    u32 v = __builtin_amdgcn_cvt_pk_fp8_f32(a, b, 0, false);
    v = __builtin_amdgcn_cvt_pk_fp8_f32(c, d, v, true);
    return v;
}
// unpack 4 fp8 bytes and accumulate into float4
__device__ inline void acc4(float4& a, u32 q) {
    f32x2 lo = __builtin_amdgcn_cvt_pk_f32_fp8(q, false);
    f32x2 hi = __builtin_amdgcn_cvt_pk_f32_fp8(q, true);
    a.x += lo[0]; a.y += lo[1]; a.z += hi[0]; a.w += hi[1];
}

// ---------- bucket-sort CSR build (fixed-capacity buckets: ONE pass over ei) ----------

// A: scatter packed (rel_dst<<SRC_BITS | src) into fixed-capacity buckets.
// bcur holds per-bucket OFFSET cursors (0-init by memset); slot = b*cap + off.
__global__ __launch_bounds__(256) void k_bscat(const int* __restrict__ ei,
                                               int* bcur, u32* __restrict__ pairs,
                                               int E, int bshift, int cap) {
    __shared__ int h[256];
    __shared__ int rb[256];
    int t = threadIdx.x;
    h[t] = 0;
    __syncthreads();
    int base = blockIdx.x * EPB;
    #pragma unroll
    for (int k = 0; k < EPB / 256; ++k) {
        int e = base + k * 256 + t;
        if (e < E) atomicAdd(&h[ei[E + e] >> bshift], 1);
    }
    __syncthreads();
    int c = h[t];
    if (c) rb[t] = t * cap + atomicAdd(&bcur[t * BCS], c);
    h[t] = 0;
    __syncthreads();
    #pragma unroll
    for (int k = 0; k < EPB / 256; ++k) {
        int e = base + k * 256 + t;
        if (e < E) {
            int d = ei[E + e];
            int b = d >> bshift;
            int p = rb[b] + atomicAdd(&h[b], 1);
            u32 rel = (u32)(d - (b << bshift));
            pairs[p] = (rel << SRC_BITS) | (u32)ei[e];
        }
    }
}

// B (fused ndeg+scan): per-bucket LDS degree histogram -> dinv + bucket-local
// exclusive scan of padded counts (pad to mult of 4) -> offs (LOCAL) + bsum[b].
__global__ __launch_bounds__(512) void k_degscan(const u32* __restrict__ pairs,
        const int* __restrict__ bcur, float* __restrict__ dinv,
        int* __restrict__ offs, int* __restrict__ bsum,
        int n, int bshift, int cap) {
    extern __shared__ int sh[];           // deg[bsz] + ss[512]
    int bsz = 1 << bshift;
    int* deg = sh;
    int* ss = sh + bsz;
    int b = blockIdx.x, b0 = b << bshift, t = threadIdx.x;
    for (int i = t; i < bsz; i += 512) deg[i] = 0;
    __syncthreads();
    int lo = b * cap, hi = lo + bcur[b * BCS];
    for (int j = lo + t; j < hi; j += 512)
        atomicAdd(&deg[pairs[j] >> SRC_BITS], 1);
    __syncthreads();
    int C = bsz >> 9;                     // items per thread (1 for bsz=512)
    int vloc[8];                          // supports bsz <= 4096
    int tsum = 0;
    for (int c = 0; c < C; ++c) {
        int i = t * C + c;
        int node = b0 + i;
        int v = 0;
        if (node < n) {
            int real = deg[i] + 1;        // +1 self-loop
            dinv[node] = 1.0f / sqrtf((float)real);
            v = (real + 3) & ~3;
        }
        vloc[c] = tsum;
        tsum += v;
    }
    ss[t] = tsum;
    for (int d = 1; d < 512; d <<= 1) {
        __syncthreads();
        int a = (t >= d) ? ss[t - d] : 0;
        __syncthreads();
        ss[t] += a;
    }
    __syncthreads();
    int tbase = ss[t] - tsum;             // exclusive
    for (int c = 0; c < C; ++c) {
        int node = b0 + t * C + c;
        if (node < n) offs[node] = tbase + vloc[c];   // bucket-local
    }
    if (t == 511) bsum[b] = ss[511];
}

// C (fused csr + pack): block-range split.
//   blocks [0, nbk):            per-bucket CSR scatter (LDS cursors, in-LDS
//                               scan of bucket totals, offs finalized ABSOLUTE,
//                               self-loop + sentinel pad)
//   blocks [nbk, nbk+npack):    fp8 pack of x (q0 = fp8(QS*dinv*x); row n = 0)
//   blocks [nbk+npack, +16):    pre-swizzled bf16 W-fragments of the 4 layers
// csr (196 blocks) and pack (51MB stream) are independent given degscan ->
// overlapping them hides pack behind csr's latency + saves a launch gap.
__global__ __launch_bounds__(512) void k_csrpack(const u32* __restrict__ pairs,
        const int* __restrict__ bcur, const int* __restrict__ bsum,
        int* __restrict__ offs, int* __restrict__ srcS,
        const float* __restrict__ x, const float* __restrict__ dinv,
        u32* __restrict__ q,
        const float* __restrict__ W0, const float* __restrict__ W1,
        const float* __restrict__ W2, const float* __restrict__ W3,
        u32* __restrict__ wt,
        int n, int nbk, int bshift, int cap, int npack) {
    int blk = blockIdx.x;
    if (blk < nbk) {
        extern __shared__ int sh[];           // cur[bsz] + end[bsz]
        __shared__ int ss[512];
        int bsz = 1 << bshift;
        int* cur = sh;
        int* endv = sh + bsz;
        int b = blk, b0 = b << bshift, t = threadIdx.x;

        int v = (t < nbk) ? bsum[t] : 0;
        ss[t] = v;
        for (int d = 1; d < 512; d <<= 1) {
            __syncthreads();
            int a = (t >= d) ? ss[t - d] : 0;
            __syncthreads();
            ss[t] += a;
        }
        __syncthreads();
        int bsumb = bsum[b];
        int base = ss[b] - bsumb;             // exclusive base of bucket b
        int nextbase = ss[b];                 // exclusive base of bucket b+1
        int total = ss[511];                  // grand total (padded)
        if (b == nbk - 1 && t == 0) offs[n] = total;

        for (int i = t; i < bsz; i += 512) {
            int node = b0 + i;
            int o = 0;
            if (node < n) {
                o = offs[node] + base;
                offs[node] = o;               // finalize absolute
            }
            cur[i] = o;
        }
        __syncthreads();
        for (int i = t; i < bsz; i += 512) {
            int node = b0 + i;
            int e;
            if (node + 1 >= n)       e = total;
            else if (i < bsz - 1)    e = cur[i + 1];
            else                     e = nextbase;
            endv[i] = e;
        }
        __syncthreads();
        int lo = b * cap, hi = lo + bcur[b * BCS];
        for (int j = lo + t; j < hi; j += 512) {
            u32 vv = pairs[j];
            int p = atomicAdd(&cur[vv >> SRC_BITS], 1);
            srcS[p] = (int)(vv & SRC_MASK);
        }
        __syncthreads();
        for (int i = t; i < bsz; i += 512) {
            int node = b0 + i;
            if (node < n) {
                int c = cur[i];
                srcS[c] = node;                              // self-loop
                int e = endv[i];
                for (int k = c + 1; k < e; ++k) srcS[k] = n; // sentinel padding
            }
        }
    } else if (blk < nbk + npack) {
        int t = (blk - nbk) * 512 + threadIdx.x;
        int totalu4 = (n + 1) * (NQ / 4);     // 8 uint4 per fp8 row
        if (t < totalu4) {
            int row = t >> 3;
            uint4 o = make_uint4(0, 0, 0, 0);
            if (row < n) {
                int cbase = (t & 7) << 4;     // 16 channels per uint4
                const float* xr = x + (size_t)row * NF + cbase;
                f32x4 f0 = __builtin_nontemporal_load((const f32x4*)(xr));
                f32x4 f1 = __builtin_nontemporal_load((const f32x4*)(xr + 4));
                f32x4 f2 = __builtin_nontemporal_load((const f32x4*)(xr + 8));
                f32x4 f3 = __builtin_nontemporal_load((const f32x4*)(xr + 12));
                float d = dinv[row] * QS;
                o.x = pack4(f0.x * d, f0.y * d, f0.z * d, f0.w * d);
                o.y = pack4(f1.x * d, f1.y * d, f1.z * d, f1.w * d);
                o.z = pack4(f2.x * d, f2.y * d, f2.z * d, f2.w * d);
                o.w = pack4(f3.x * d, f3.y * d, f3.z * d, f3.w * d);
            }
            ((uint4*)q)[t] = o;
        }
    } else {
        int t = (blk - nbk - npack) * 512 + threadIdx.x;
        if (t < 4 * 2048) {
            int layer = t >> 11;
            int rem = t & 2047;               // = (nt*4+ks)*64 + lane
            int lane = rem & 63;
            int ks = (rem >> 6) & 3;
            int nt = rem >> 8;
            const float* W = layer == 0 ? W0 : layer == 1 ? W1
                           : layer == 2 ? W2 : W3;
            int nn = nt * 16 + (lane & 15);
            int k0 = ks * 32 + (lane >> 4) * 8;
            uint4 o;
            o.x = pack2(W[(k0 + 0) * NF + nn], W[(k0 + 1) * NF + nn]);
            o.y = pack2(W[(k0 + 2) * NF + nn], W[(k0 + 3) * NF + nn]);
            o.z = pack2(W[(k0 + 4) * NF + nn], W[(k0 + 5) * NF + nn]);
            o.w = pack2(W[(k0 + 6) * NF + nn], W[(k0 + 7) * NF + nn]);
            ((uint4*)wt)[t] = o;
        }
    }
}

// ---------- fused layer: fp8 gather-sum -> bf16 LDS tile -> MFMA GEMM -> epilogue ----------
// hin rows are fp8 e4m3 of QS*dinv*h (row n zeros; 128B = ONE cache line/edge).
// Gather = r7 proven form: 32 lanes/row, 4B/lane, 8 edges/iter + 4-tail.
// Concurrency-raising variants all measured SLOWER (r5 NT, r6 chains, r8 wide
// lanes, r9 slice-phasing) — limiter is per-CU outstanding-miss tracking x
// latency with L2 hit rate already near its structural ceiling (~52% vs ~60%
// ideal for 20-fold reuse over 8 XCDs). This is the floor for this structure.
__global__ __launch_bounds__(256, 8) void k_fused(
        const u32* __restrict__ hin, const int* __restrict__ offs,
        const int* __restrict__ srcS, const float* __restrict__ dinv,
        const u32* __restrict__ wt, const float* __restrict__ bias,
        u32* __restrict__ out, int* tctr, int n, int ntiles, int last) {
    __shared__ __align__(16) u32 buf[TROWS * CRS];   // 16.9 KB union As/Cs
    __shared__ int stile;
    float* Cs = (float*)buf;
    int tid = threadIdx.x;
    int grp = tid >> 5;          // 0..7 (gather/epilogue groups)
    int lane32 = tid & 31;
    int c4 = lane32 << 2;        // channel offset (4 ch/lane)
    int cu = lane32 << 1;        // uint offset within bf16 row
    int cq = lane32;             // uint offset within fp8 row
    int wv = tid >> 6;           // wave 0..3 (MFMA phase)
    int lane = tid & 63;
    int m0 = (wv & 1) * 16;      // M-tile base row
    int nh = wv >> 1;            // N-half (cols nh*64..+64)
    int mrow = lane & 15, quad = lane >> 4;

    float4 bv = *(const float4*)(bias + c4);   // constant across tiles

    for (;;) {
        if (tid == 0) stile = atomicAdd(tctr, 1);
        __syncthreads();
        int tile = stile;
        if (tile >= ntiles) break;
        int row0 = tile * TROWS;

        // ---- gather/sum phase (fp8 load, fp32 acc, bf16 As) ----
        #pragma unroll
        for (int i = 0; i < 4; ++i) {
            int r = grp * 4 + i;
            int node = row0 + r;
            float4 acc = make_float4(0.f, 0.f, 0.f, 0.f);
            if (node < n) {
                int b = offs[node], e = offs[node + 1];
                int j = b;
                for (; j + 8 <= e; j += 8) {
                    int4 sa = *(const int4*)(srcS + j);
                    int4 sb = *(const int4*)(srcS + j + 4);
                    u32 q0 = hin[(size_t)sa.x * NQ + cq];
                    u32 q1 = hin[(size_t)sa.y * NQ + cq];
                    u32 q2 = hin[(size_t)sa.z * NQ + cq];
                    u32 q3 = hin[(size_t)sa.w * NQ + cq];
                    u32 q4 = hin[(size_t)sb.x * NQ + cq];
                    u32 q5 = hin[(size_t)sb.y * NQ + cq];
                    u32 q6 = hin[(size_t)sb.z * NQ + cq];
                    u32 q7 = hin[(size_t)sb.w * NQ + cq];
                    acc4(acc, q0); acc4(acc, q1); acc4(acc, q2); acc4(acc, q3);
                    acc4(acc, q4); acc4(acc, q5); acc4(acc, q6); acc4(acc, q7);
                }
                if (j < e) {                 // exactly 4 remain (count % 8 == 4)
                    int4 sa = *(const int4*)(srcS + j);
                    u32 q0 = hin[(size_t)sa.x * NQ + cq];
                    u32 q1 = hin[(size_t)sa.y * NQ + cq];
                    u32 q2 = hin[(size_t)sa.z * NQ + cq];
                    u32 q3 = hin[(size_t)sa.w * NQ + cq];
                    acc4(acc, q0); acc4(acc, q1); acc4(acc, q2); acc4(acc, q3);
                }
                float dn = dinv[node];
                acc.x *= dn; acc.y *= dn; acc.z *= dn; acc.w *= dn;
            }
            b4 o; o.x = pack2(acc.x, acc.y); o.y = pack2(acc.z, acc.w);
            *(b4*)(buf + r * ARS + cu) = o;
        }
        __syncthreads();

        // ---- MFMA GEMM phase ----
        f32x4 a0 = {0.f, 0.f, 0.f, 0.f}, a1 = a0, a2 = a0, a3 = a0;
        #pragma unroll
        for (int ks = 0; ks < 4; ++ks) {
            bf16x8 a = *(const bf16x8*)(buf + (m0 + mrow) * ARS + ks * 16 + quad * 4);
            const u32* wb = wt + (((nh * 4) * 4 + ks) * 64 + lane) * 4;
            bf16x8 b0 = *(const bf16x8*)(wb);
            bf16x8 b1 = *(const bf16x8*)(wb + 1024);   // nt+1 -> +256 uint4
            bf16x8 b2 = *(const bf16x8*)(wb + 2048);
            bf16x8 b3 = *(const bf16x8*)(wb + 3072);
            a0 = __builtin_amdgcn_mfma_f32_16x16x32_bf16(a, b0, a0, 0, 0, 0);
            a1 = __builtin_amdgcn_mfma_f32_16x16x32_bf16(a, b1, a1, 0, 0, 0);
            a2 = __builtin_amdgcn_mfma_f32_16x16x32_bf16(a, b2, a2, 0, 0, 0);
            a3 = __builtin_amdgcn_mfma_f32_16x16x32_bf16(a, b3, a3, 0, 0, 0);
        }
        __syncthreads();   // all As reads done before Cs overwrites the union

        // C frags -> LDS (col = lane&15, row = quad*4+reg)
        #pragma unroll
        for (int nt = 0; nt < 4; ++nt) {
            f32x4 av = nt == 0 ? a0 : nt == 1 ? a1 : nt == 2 ? a2 : a3;
            int col = (nh * 4 + nt) * 16 + mrow;
            #pragma unroll
            for (int rg = 0; rg < 4; ++rg)
                Cs[(m0 + quad * 4 + rg) * CRS + col] = av[rg];
        }
        __syncthreads();

        // ---- epilogue: descale + bias + ReLU, pack, plain store ----
        #pragma unroll
        for (int j = 0; j < 4; ++j) {
            int r = grp * 4 + j;
            int gr = row0 + r;
            if (gr <= n) {
                if (last) {
                    b4 o; o.x = 0u; o.y = 0u;
                    if (gr < n) {
                        float4 v = *(const float4*)(Cs + r * CRS + c4);
                        float ox = fmaxf(v.x * QIS + bv.x, 0.f);
                        float oy = fmaxf(v.y * QIS + bv.y, 0.f);
                        float oz = fmaxf(v.z * QIS + bv.z, 0.f);
                        float ow = fmaxf(v.w * QIS + bv.w, 0.f);
                        o.x = pack2(ox, oy);
                        o.y = pack2(oz, ow);
                    }
                    *(b4*)(out + (size_t)gr * NU + cu) = o;   // gr==n keeps sentinel 0
                } else {
                    u32 o = 0u;
                    if (gr < n) {
                        float4 v = *(const float4*)(Cs + r * CRS + c4);
                        float sc = dinv[gr] * QS;
                        float ox = fmaxf(v.x * QIS + bv.x, 0.f) * sc;
                        float oy = fmaxf(v.y * QIS + bv.y, 0.f) * sc;
                        float oz = fmaxf(v.z * QIS + bv.z, 0.f) * sc;
                        float ow = fmaxf(v.w * QIS + bv.w, 0.f) * sc;
                        o = pack4(ox, oy, oz, ow);
                    }
                    out[(size_t)gr * NQ + cq] = o;            // gr==n keeps sentinel 0
                }
            }
        }
        __syncthreads();   // buf reused as As next tile; stile rewrite safe
    }
}

// ---------- fused pool + head (batch sorted -> contiguous ranges; bounds inline) ----------

__global__ __launch_bounds__(256) void k_poolfinal(const u32* __restrict__ h,
        const int* __restrict__ batch, const float* __restrict__ linW,
        const float* __restrict__ linb, float* __restrict__ outp, int N) {
    int g = blockIdx.x;
    int tid = threadIdx.x;
    __shared__ int sb[2];
    if (tid < 2) {                       // lower_bound(batch, g+tid)
        int target = g + tid;
        int lo = 0, hi = N;
        while (lo < hi) {
            int mid = (lo + hi) >> 1;
            if (batch[mid] < target) lo = mid + 1; else hi = mid;
        }
        sb[tid] = lo;
    }
    __syncthreads();
    int b = sb[0], e = sb[1];

    int grp = tid >> 5, lane = tid & 31;
    int c4 = lane << 2, cu = lane << 1;
    float4 acc = make_float4(0.f, 0.f, 0.f, 0.f);
    for (int i = b + grp; i < e; i += 8) {
        b4 v = *(const b4*)(h + (size_t)i * NU + cu);
        acc.x += bflo(v.x); acc.y += bfhi(v.x);
        acc.z += bflo(v.y); acc.w += bfhi(v.y);
    }
    __shared__ float red[8][NF];
    *(float4*)(&red[grp][c4]) = acc;
    __syncthreads();

    float v0 = 0.f, v1 = 0.f;
    if (tid < NF) {
        float s = 0.f;
        #pragma unroll
        for (int gg = 0; gg < 8; ++gg) s += red[gg][tid];
        v0 = s * linW[tid * 2 + 0];
        v1 = s * linW[tid * 2 + 1];
    }
    #pragma unroll
    for (int d = 32; d > 0; d >>= 1) {
        v0 += __shfl_down(v0, d);
        v1 += __shfl_down(v1, d);
    }
    __shared__ float sv[8];
    if ((tid & 63) == 0) { sv[(tid >> 6) * 2] = v0; sv[(tid >> 6) * 2 + 1] = v1; }
    __syncthreads();
    if (tid == 0) {
        float inv = 1.0f / fmaxf((float)(e - b), 1.0f);
        outp[g * 2 + 0] = (sv[0] + sv[2]) * inv + linb[0];
        outp[g * 2 + 1] = (sv[1] + sv[3]) * inv + linb[1];
    }
}

// ---------- launcher ----------

extern "C" void kernel_launch(void* const* d_in, const int* in_sizes, int n_in,
                              void* d_out, int out_size, void* d_ws, size_t ws_size,
                              hipStream_t stream) {
    const float* x     = (const float*)d_in[0];
    const int*   ei    = (const int*)d_in[1];
    const int*   batch = (const int*)d_in[2];
    const float* Wl[4] = {(const float*)d_in[3], (const float*)d_in[5],
                          (const float*)d_in[7], (const float*)d_in[9]};
    const float* bl[4] = {(const float*)d_in[4], (const float*)d_in[6],
                          (const float*)d_in[8], (const float*)d_in[10]};
    const float* linW  = (const float*)d_in[11];
    const float* linb  = (const float*)d_in[12];
    float* out = (float*)d_out;

    const int N  = in_sizes[2];
    const int E  = in_sizes[1] / 2;
    const int G  = out_size / 2;

    // bucket geometry: <=256 buckets, each 1<<bshift nodes
    int bshift = 9;
    while (((N + (1 << bshift) - 1) >> bshift) > 256) ++bshift;
    int nbk = (N + (1 << bshift) - 1) >> bshift;
    int bsz = 1 << bshift;
    // fixed bucket capacity: 1.25x mean + 1024 slack (>=30 sigma), 256-aligned
    int cap = ((E / nbk) * 5 / 4 + 1024 + 255) & ~255;

    // carve workspace (256B-aligned slices)
    char* p = (char*)d_ws;
    auto carve = [&](size_t bytes) -> char* {
        char* r = p;
        p += (bytes + 255) & ~(size_t)255;
        return r;
    };
    float* dinv   = (float*)carve((size_t)N * 4);
    int*   offs   = (int*)  carve((size_t)(N + 1) * 4);
    int*   bsum   = (int*)  carve(512 * 4);
    int*   bcur   = (int*)  carve(256 * BCS * 4);   // |-- contiguous zeroed region
    int*   tctr   = (int*)  carve(4 * 4);           // |-- end (dyn tile counters)
    u32*   wt     = (u32*)  carve(4 * 2048 * 16);              // bf16 W fragments
    int*   srcS   = (int*)  carve((size_t)(E + 4 * (size_t)N) * 4);   // padded CSR
    u32*   bufA   = (u32*)  carve((size_t)(N + 1) * NU * 4);   // ping (fp8/bf16 rows)
    u32*   bufB   = (u32*)  carve((size_t)(N + 1) * NU * 4);   // pong
    u32*   pairs  = bufB;   // fixed-cap bucketed edges; bufB free until layer-0 out

    size_t zbytes = (char*)(tctr + 4) - (char*)bcur;   // bcur..tctr contiguous
    (void)hipMemsetAsync(bcur, 0, zbytes, stream);

    int nblkE = (E + EPB - 1) / EPB;
    k_bscat<<<nblkE, 256, 0, stream>>>(ei, bcur, pairs, E, bshift, cap);
    k_degscan<<<nbk, 512, (bsz + 512) * 4, stream>>>(pairs, bcur, dinv, offs,
                                                     bsum, N, bshift, cap);

    int totalu4 = (N + 1) * (NQ / 4);
    int npack = (totalu4 + 511) / 512;
    int nwt = (4 * 2048 + 511) / 512;                 // 16 blocks
    k_csrpack<<<nbk + npack + nwt, 512, 2 * bsz * 4, stream>>>(
        pairs, bcur, bsum, offs, srcS, x, dinv, bufA,
        Wl[0], Wl[1], Wl[2], Wl[3], wt, N, nbk, bshift, cap, npack);

    int ntiles = (N + 1 + TROWS - 1) / TROWS;
    int ngrid = ntiles < 2048 ? ntiles : 2048;
    const u32* hin = bufA;
    u32* hout = bufB;
    for (int l = 0; l < 4; ++l) {
        k_fused<<<ngrid, 256, 0, stream>>>(hin, offs, srcS, dinv, wt + l * 8192,
                                           bl[l], hout, tctr + l, N, ntiles, l == 3);
        hin = hout;
        hout = (hout == bufA) ? bufB : bufA;
    }

    k_poolfinal<<<G, 256, 0, stream>>>(hin, batch, linW, linb, out, N);
}